// Round 13
// baseline (154.275 us; speedup 1.0000x reference)
//
#include <hip/hip_runtime.h>
#include <cstdint>

typedef unsigned short u16;
typedef __bf16 bf16x8 __attribute__((ext_vector_type(8)));
typedef float f32x4 __attribute__((ext_vector_type(4)));

#define B_   8
#define N_   8192
#define S_   2048
#define D1_  128
#define D2_  256
#define INCH 384
#define M_   (B_ * N_)   // 65536 rows total

__device__ __forceinline__ u16 f2bf(float f) {
  union { float f; unsigned u; } a; a.f = f;
  unsigned u = a.u;
  return (u16)((u + 0x7fffu + ((u >> 16) & 1u)) >> 16);  // RNE
}
__device__ __forceinline__ float bf2f(u16 h) {
  union { unsigned u; float f; } a; a.u = ((unsigned)h) << 16;
  return a.f;
}
__device__ __forceinline__ unsigned pack2(float lo, float hi) {
  return (unsigned)f2bf(lo) | ((unsigned)f2bf(hi) << 16);
}

__device__ __forceinline__ void async16(const void* g, void* l) {
  __builtin_amdgcn_global_load_lds((const __attribute__((address_space(1))) unsigned int*)g,
                                   (__attribute__((address_space(3))) unsigned int*)l,
                                   16, 0, 0);
}

// Branchless top-3 insert; strict-< cascade semantics (lowest index on ties).
__device__ __forceinline__ void top3_bl(float d, int s,
                                        float& d0, float& d1, float& d2,
                                        int& i0, int& i1, int& i2) {
  const bool c0 = d < d0, c1 = d < d1, c2 = d < d2;
  const float n1 = __builtin_amdgcn_fmed3f(d, d0, d1);
  const float n2 = __builtin_amdgcn_fmed3f(d, d1, d2);
  i2 = c1 ? i1 : (c2 ? s : i2);   // reverse order: RHS uses old i1/i0
  i1 = c0 ? i0 : (c1 ? s : i1);
  i0 = c0 ? s : i0;
  d0 = fminf(d, d0);
  d1 = n1;
  d2 = n2;
}

// ------------------------------------------- fused 3-NN + interpolate + concat
// Q=4 points/thread, 16 chunks x 128 candidates. LDS-pipe model (round-11):
// scan traffic = 16B x candidates x points / Q per block; Q=2 cost ~20.6us/CU
// of ds_read_b128 time (85 B/cyc) vs 24us VALU floor. Q=4 halves LDS traffic
// and quadruples VALU per load (56 inst) so load latency hides in-wave.
// launch_bounds(1024,4): 128-VGPR budget so the ~90 live regs (4 triples +
// consts + 8-wide prefetch) fit — round-11's VGPR=32 clamp serialized loads.
// All state arrays only see constant (fully unrolled) indices -> registers.
// Also folds: weight->bf16 conversion, BN-stats zeroing (block 0,0).
__global__ __launch_bounds__(1024, 4) void knn_interp_kernel(
    const float* __restrict__ xyz1, const float* __restrict__ xyz2,
    const float* __restrict__ points1, const float* __restrict__ points2,
    u16* __restrict__ xcat,
    const float* __restrict__ w0, const float* __restrict__ w1,
    u16* __restrict__ w0b, u16* __restrict__ w1b,
    float* __restrict__ stats) {
  __shared__ float4 sp[16 * 131];   // stride 131: chunk bases 2-way bank alias (free)
  const int b = blockIdx.y;
  const int t = threadIdx.x;
  {  // folded weight conversion: 131072 elements over 262144 threads
    int gid = (b * gridDim.x + blockIdx.x) * 1024 + t;
    if (gid < 256 * INCH) w0b[gid] = f2bf(w0[gid]);
    else if (gid < 256 * INCH + 128 * 256) {
      int k2 = gid - 256 * INCH;
      w1b[k2] = f2bf(w1[k2]);
    }
  }
  if (blockIdx.x == 0 && b == 0) {          // folded stats zeroing (replays!)
    if (t < 768) stats[t] = 0.f;
  }
#pragma unroll
  for (int k = 0; k < 2; ++k) {
    int s = t + k * 1024;
    const float* q = xyz2 + ((size_t)b * S_ + s) * 3;
    float x = q[0], y = q[1], z = q[2];
    sp[(s >> 7) * 131 + (s & 127)] = make_float4(x, y, z, fmaf(x, x, fmaf(y, y, z * z)));
  }
  __syncthreads();
  const int pw = t >> 4;     // point-quad within block [0,64)
  const int ck = t & 15;     // S-chunk [0,16)
  const int n0 = blockIdx.x * 256 + pw * 4;
  const int pbase = b * N_ + n0;
  float nx[4], ny[4], nz[4], p2[4];
#pragma unroll
  for (int pt = 0; pt < 4; ++pt) {
    const float px = xyz1[(pbase + pt) * 3 + 0];
    const float py = xyz1[(pbase + pt) * 3 + 1];
    const float pz = xyz1[(pbase + pt) * 3 + 2];
    nx[pt] = -2.f * px; ny[pt] = -2.f * py; nz[pt] = -2.f * pz;
    p2[pt] = fmaf(px, px, fmaf(py, py, pz * pz));
  }
  float td0[4], td1[4], td2[4];
  int ti0[4], ti1[4], ti2[4];
#pragma unroll
  for (int pt = 0; pt < 4; ++pt) {
    td0[pt] = 3e38f; td1[pt] = 3e38f; td2[pt] = 3e38f;
    ti0[pt] = 0; ti1[pt] = 0; ti2[pt] = 0;
  }
  const float4* bp = &sp[ck * 131];
  for (int s = 0; s < 128; s += 8) {
    float4 qv[8];
#pragma unroll
    for (int j = 0; j < 8; ++j) qv[j] = bp[s + j];   // 8 b128 loads in flight
#pragma unroll
    for (int j = 0; j < 8; ++j) {
      const float4 q = qv[j];
#pragma unroll
      for (int pt = 0; pt < 4; ++pt) {
        float key = fmaf(q.x, nx[pt], fmaf(q.y, ny[pt], fmaf(q.z, nz[pt], q.w)));
        top3_bl(key, s + j, td0[pt], td1[pt], td2[pt], ti0[pt], ti1[pt], ti2[pt]);
      }
    }
  }
  const int soff = ck * 128;
#pragma unroll
  for (int pt = 0; pt < 4; ++pt) {
    ti0[pt] += soff; ti1[pt] += soff; ti2[pt] += soff;
  }
  // XOR-butterfly merge: after masks 1,2,4,8 all 16 lanes hold the merged top-3
#pragma unroll
  for (int m = 1; m <= 8; m <<= 1) {
#pragma unroll
    for (int pt = 0; pt < 4; ++pt) {
      float e0 = __shfl_xor(td0[pt], m), e1 = __shfl_xor(td1[pt], m), e2 = __shfl_xor(td2[pt], m);
      int j0 = __shfl_xor(ti0[pt], m), j1 = __shfl_xor(ti1[pt], m), j2 = __shfl_xor(ti2[pt], m);
      top3_bl(e0, j0, td0[pt], td1[pt], td2[pt], ti0[pt], ti1[pt], ti2[pt]);
      top3_bl(e1, j1, td0[pt], td1[pt], td2[pt], ti0[pt], ti1[pt], ti2[pt]);
      top3_bl(e2, j2, td0[pt], td1[pt], td2[pt], ti0[pt], ti1[pt], ti2[pt]);
    }
  }
  // ---- weights + gather + concat per point (all 16 lanes hold final top-3)
  const float* P2b = points2 + (size_t)b * S_ * D2_;
#pragma unroll
  for (int pt = 0; pt < 4; ++pt) {
    float dd0 = fmaxf(td0[pt] + p2[pt], 1e-10f);
    float dd1 = fmaxf(td1[pt] + p2[pt], 1e-10f);
    float dd2 = fmaxf(td2[pt] + p2[pt], 1e-10f);
    float v0 = 1.f / dd0, v1 = 1.f / dd1, v2 = 1.f / dd2;
    float inv = 1.f / (v0 + v1 + v2);
    const float w_0 = v0 * inv, w_1 = v1 * inv, w_2 = v2 * inv;
    const int p = pbase + pt;
    const float* Q0 = P2b + (size_t)ti0[pt] * D2_;
    const float* Q1 = P2b + (size_t)ti1[pt] * D2_;
    const float* Q2 = P2b + (size_t)ti2[pt] * D2_;
    u16* xr = xcat + (size_t)p * INCH;
    const float4* P1 = (const float4*)(points1 + (size_t)p * D1_);
#pragma unroll
    for (int j = 0; j < 2; ++j) {       // points1 half: 32 float4 over 16 lanes
      int cchunk = j * 16 + ck;
      float4 v = P1[cchunk];
      *(uint2*)&xr[cchunk * 4] = make_uint2(pack2(v.x, v.y), pack2(v.z, v.w));
    }
#pragma unroll
    for (int j = 0; j < 4; ++j) {       // interp half: 64 float4 over 16 lanes
      int cchunk = j * 16 + ck;
      float4 qa = *(const float4*)(Q0 + cchunk * 4);
      float4 qb = *(const float4*)(Q1 + cchunk * 4);
      float4 qc = *(const float4*)(Q2 + cchunk * 4);
      float r0 = fmaf(w_0, qa.x, fmaf(w_1, qb.x, w_2 * qc.x));
      float r1 = fmaf(w_0, qa.y, fmaf(w_1, qb.y, w_2 * qc.y));
      float r2 = fmaf(w_0, qa.z, fmaf(w_1, qb.z, w_2 * qc.z));
      float r3 = fmaf(w_0, qa.w, fmaf(w_1, qb.w, w_2 * qc.w));
      *(uint2*)&xr[D1_ + cchunk * 4] = make_uint2(pack2(r0, r1), pack2(r2, r3));
    }
  }
}

// ---------------------------------------------------------------- MFMA GEMM
// C[M,NT] = A[M,K] * W[NT,K]^T, FULL-WIDTH N tile (A read exactly once).
// BM=128, BN=NT, BK=64. THREADS = NT*2. Wave tile 64x64, acc[4][4] f32x4.
// FUSE: prologue computes BN scale/shift IN-KERNEL from gsum/gsq+gamma/beta
// (stats final at kernel boundary) — kills the bn_finalize launch; A-staging
// then applies BN+ReLU in regs. Non-FUSE uses global_load_lds w=16.
// NOTE: no __threadfence / in-kernel stats finalize for OWN stats (round-4
// lesson: per-block agent-scope release = buffer_wbl2 serialization).
template <int K, int NT, bool FUSE, int MW>
__global__ __launch_bounds__(NT * 2, MW) void gemm_bn(const u16* __restrict__ A,
                                                      const u16* __restrict__ W,
                                                      u16* __restrict__ Y,
                                                      float* __restrict__ gsum,
                                                      float* __restrict__ gsq,
                                                      const float* __restrict__ bnsum,
                                                      const float* __restrict__ bnsq,
                                                      const float* __restrict__ bngam,
                                                      const float* __restrict__ bnbet) {
  constexpr int THREADS = NT * 2;
  constexpr int RPP = THREADS / 8;   // rows per staging pass (8 thr x 16B = 64 cols)
  constexpr int AP = 128 / RPP;      // A staging passes
  constexpr int WP = NT / RPP;       // W staging passes
  constexpr int WCN = NT / 64;       // wave columns
  __shared__ u16 As[128 * 64];
  __shared__ u16 Ws[NT * 64];
  __shared__ float s_sum[NT];
  __shared__ float s_sq[NT];
  __shared__ float s_scale[FUSE ? K : 1];
  __shared__ float s_shift[FUSE ? K : 1];
  const int tid = threadIdx.x;
  const int lane = tid & 63, wid = tid >> 6;
  const int wr = wid / WCN, wc = wid % WCN;
  const int brow = blockIdx.x * 128;
  const int rr = tid >> 3, ss = tid & 7;
  const int ch = ss ^ (rr & 7);            // inverse-swizzled source chunk
  f32x4 acc[4][4] = {};

  if constexpr (FUSE) {
    // K == 256 == THREADS: one channel per thread
    float sm = bnsum[tid] * (1.f / 65536.f);
    float vr = bnsq[tid] * (1.f / 65536.f) - sm * sm;   // biased, as reference
    float sc = bngam[tid] * rsqrtf(vr + 1e-5f);
    s_scale[tid] = sc;
    s_shift[tid] = bnbet[tid] - sm * sc;
    __syncthreads();
  }

  for (int kt = 0; kt < K / 64; ++kt) {
    if (kt) __syncthreads();
    if constexpr (FUSE) {
      const float4 sc0 = *(const float4*)&s_scale[kt * 64 + ch * 8];
      const float4 sc1 = *(const float4*)&s_scale[kt * 64 + ch * 8 + 4];
      const float4 sh0 = *(const float4*)&s_shift[kt * 64 + ch * 8];
      const float4 sh1 = *(const float4*)&s_shift[kt * 64 + ch * 8 + 4];
#pragma unroll
      for (int it = 0; it < AP; ++it) {
        int row = it * RPP + rr;
        uint4 raw = *(const uint4*)&A[(size_t)(brow + row) * K + kt * 64 + ch * 8];
        auto bnr = [](unsigned u, float s, float t) {
          return fmaxf(fmaf(bf2f((u16)u), s, t), 0.f);
        };
        unsigned o0 = pack2(bnr(raw.x & 0xffff, sc0.x, sh0.x), bnr(raw.x >> 16, sc0.y, sh0.y));
        unsigned o1 = pack2(bnr(raw.y & 0xffff, sc0.z, sh0.z), bnr(raw.y >> 16, sc0.w, sh0.w));
        unsigned o2 = pack2(bnr(raw.z & 0xffff, sc1.x, sh1.x), bnr(raw.z >> 16, sc1.y, sh1.y));
        unsigned o3 = pack2(bnr(raw.w & 0xffff, sc1.z, sh1.z), bnr(raw.w >> 16, sc1.w, sh1.w));
        *(uint4*)((char*)As + (size_t)(it * THREADS + tid) * 16) = make_uint4(o0, o1, o2, o3);
      }
    } else {
#pragma unroll
      for (int it = 0; it < AP; ++it) {
        int row = it * RPP + rr;
        async16(&A[(size_t)(brow + row) * K + kt * 64 + ch * 8], &As[(it * THREADS + tid) * 8]);
      }
    }
#pragma unroll
    for (int it = 0; it < WP; ++it) {
      int row = it * RPP + rr;
      async16(&W[(size_t)row * K + kt * 64 + ch * 8], &Ws[(it * THREADS + tid) * 8]);
    }
    __syncthreads();
#pragma unroll
    for (int ks = 0; ks < 2; ++ks) {
      bf16x8 af[4], wf[4];
#pragma unroll
      for (int i = 0; i < 4; ++i) {
        int ra = wr * 64 + i * 16 + (lane & 15);
        int ca = ks * 4 + (lane >> 4);
        af[i] = *(const bf16x8*)&As[ra * 64 + ((ca ^ (ra & 7)) * 8)];
        int rw = wc * 64 + i * 16 + (lane & 15);
        wf[i] = *(const bf16x8*)&Ws[rw * 64 + ((ca ^ (rw & 7)) * 8)];
      }
#pragma unroll
      for (int mi = 0; mi < 4; ++mi)
#pragma unroll
        for (int ni = 0; ni < 4; ++ni)
          acc[mi][ni] = __builtin_amdgcn_mfma_f32_16x16x32_bf16(af[mi], wf[ni], acc[mi][ni], 0, 0, 0);
    }
  }

  // epilogue: store bf16 + block-level BN partial sums
  __syncthreads();
  if (tid < NT) { s_sum[tid] = 0.f; s_sq[tid] = 0.f; }
  __syncthreads();
#pragma unroll
  for (int ni = 0; ni < 4; ++ni) {
    int coll = wc * 64 + ni * 16 + (lane & 15);
    float ps = 0.f, pq = 0.f;
#pragma unroll
    for (int mi = 0; mi < 4; ++mi) {
      int rowl = wr * 64 + mi * 16 + ((lane >> 4) << 2);
#pragma unroll
      for (int q = 0; q < 4; ++q) {
        float v = acc[mi][ni][q];
        ps += v; pq += v * v;
        Y[(size_t)(brow + rowl + q) * NT + coll] = f2bf(v);
      }
    }
    atomicAdd(&s_sum[coll], ps);
    atomicAdd(&s_sq[coll], pq);
  }
  __syncthreads();
  if (tid < NT) {
    unsafeAtomicAdd(&gsum[tid], s_sum[tid]);
    unsafeAtomicAdd(&gsq[tid], s_sq[tid]);
  }
}

// ------------------------------------------------- BN+ReLU -> f32 output
// Prologue computes scale/shift from stats in-kernel (stats final at kernel
// boundary) — kills the second bn_finalize launch.
__global__ __launch_bounds__(256) void bn_out_kernel(const u16* __restrict__ y,
                                                     const float* __restrict__ gsum,
                                                     const float* __restrict__ gsq,
                                                     const float* __restrict__ gamma,
                                                     const float* __restrict__ beta,
                                                     float* __restrict__ out) {
  __shared__ float s_sc[128], s_sh[128];
  if (threadIdx.x < 128) {
    int c = threadIdx.x;
    float sm = gsum[c] * (1.f / 65536.f);
    float vr = gsq[c] * (1.f / 65536.f) - sm * sm;   // biased, as reference
    float sc = gamma[c] * rsqrtf(vr + 1e-5f);
    s_sc[c] = sc;
    s_sh[c] = beta[c] - sm * sc;
  }
  __syncthreads();
  const int idx = blockIdx.x * 256 + threadIdx.x;
  uint4 v = ((const uint4*)y)[idx];
  const int c0 = (idx * 8) & 127;
  unsigned w[4] = {v.x, v.y, v.z, v.w};
  float o[8];
#pragma unroll
  for (int j = 0; j < 4; ++j) {
    o[2 * j]     = fmaxf(fmaf(bf2f((u16)(w[j] & 0xffff)), s_sc[c0 + 2 * j],     s_sh[c0 + 2 * j]),     0.f);
    o[2 * j + 1] = fmaxf(fmaf(bf2f((u16)(w[j] >> 16)),    s_sc[c0 + 2 * j + 1], s_sh[c0 + 2 * j + 1]), 0.f);
  }
  float4* op = (float4*)(out + (size_t)idx * 8);
  op[0] = make_float4(o[0], o[1], o[2], o[3]);
  op[1] = make_float4(o[4], o[5], o[6], o[7]);
}

extern "C" void kernel_launch(void* const* d_in, const int* in_sizes, int n_in,
                              void* d_out, int out_size, void* d_ws, size_t ws_size,
                              hipStream_t stream) {
  const float* xyz1    = (const float*)d_in[0];
  const float* xyz2    = (const float*)d_in[1];
  const float* points1 = (const float*)d_in[2];
  const float* points2 = (const float*)d_in[3];
  const float* w0      = (const float*)d_in[4];
  // b0 (d_in[5]) / b1 (d_in[9]) are mathematically cancelled by training-mode BN
  const float* gamma0  = (const float*)d_in[6];
  const float* beta0   = (const float*)d_in[7];
  const float* w1      = (const float*)d_in[8];
  const float* gamma1  = (const float*)d_in[10];
  const float* beta1   = (const float*)d_in[11];

  char* ws = (char*)d_ws;
  u16* xcat = (u16*)ws;  ws += (size_t)M_ * INCH * 2;   // 50.3 MB
  u16* y0   = (u16*)ws;  ws += (size_t)M_ * 256 * 2;    // 33.6 MB
  u16* y1   = (u16*)ws;  ws += (size_t)M_ * 128 * 2;    // 16.8 MB
  u16* w0b = (u16*)ws;   ws += 256 * INCH * 2;
  u16* w1b = (u16*)ws;   ws += 128 * 256 * 2;
  float* stats = (float*)ws; ws += 768 * 4;  // sum0[256] sq0[256] sum1[128] sq1[128]

  float* sum0 = stats,       *sq0 = stats + 256;
  float* sum1 = stats + 512, *sq1 = stats + 640;

  // stats zeroing is folded into knn_interp block (0,0) — no memset dispatch

  knn_interp_kernel<<<dim3(N_ / 256, B_), 1024, 0, stream>>>(
      xyz1, xyz2, points1, points2, xcat, w0, w1, w0b, w1b, stats);

  gemm_bn<INCH, 256, false, 4><<<dim3(M_ / 128), 512, 0, stream>>>(
      xcat, w0b, y0, sum0, sq0, nullptr, nullptr, nullptr, nullptr);

  // gemm2 consumes RAW y0; BN0 scale/shift computed in-kernel from stats
  gemm_bn<256, 128, true, 2><<<dim3(M_ / 128), 256, 0, stream>>>(
      y0, w1b, y1, sum1, sq1, sum0, sq0, gamma0, beta0);

  // bn_out computes BN1 scale/shift in-kernel from stats
  bn_out_kernel<<<(M_ * 128 / 8) / 256, 256, 0, stream>>>(
      y1, sum1, sq1, gamma1, beta1, (float*)d_out);
}

// Round 16
// 144.090 us; speedup vs baseline: 1.0707x; 1.0707x over previous
//
#include <hip/hip_runtime.h>
#include <cstdint>

typedef unsigned short u16;
typedef __bf16 bf16x8 __attribute__((ext_vector_type(8)));
typedef float f32x4 __attribute__((ext_vector_type(4)));

#define B_   8
#define N_   8192
#define S_   2048
#define D1_  128
#define D2_  256
#define INCH 384
#define M_   (B_ * N_)   // 65536 rows total

__device__ __forceinline__ u16 f2bf(float f) {
  union { float f; unsigned u; } a; a.f = f;
  unsigned u = a.u;
  return (u16)((u + 0x7fffu + ((u >> 16) & 1u)) >> 16);  // RNE
}
__device__ __forceinline__ float bf2f(u16 h) {
  union { unsigned u; float f; } a; a.u = ((unsigned)h) << 16;
  return a.f;
}
__device__ __forceinline__ unsigned pack2(float lo, float hi) {
  return (unsigned)f2bf(lo) | ((unsigned)f2bf(hi) << 16);
}

__device__ __forceinline__ void async16(const void* g, void* l) {
  __builtin_amdgcn_global_load_lds((const __attribute__((address_space(1))) unsigned int*)g,
                                   (__attribute__((address_space(3))) unsigned int*)l,
                                   16, 0, 0);
}

// Branchless top-3 insert; strict-< cascade semantics (lowest index on ties).
// EXACT — round-14 lesson: selection must be exact; a flipped near-tie swaps
// FEATURES (O(1) per channel), not just weights, blowing the bf16 threshold.
__device__ __forceinline__ void top3_bl(float d, int s,
                                        float& d0, float& d1, float& d2,
                                        int& i0, int& i1, int& i2) {
  const bool c0 = d < d0, c1 = d < d1, c2 = d < d2;
  const float n1 = __builtin_amdgcn_fmed3f(d, d0, d1);
  const float n2 = __builtin_amdgcn_fmed3f(d, d1, d2);
  i2 = c1 ? i1 : (c2 ? s : i2);   // reverse order: RHS uses old i1/i0
  i1 = c0 ? i0 : (c1 ? s : i1);
  i0 = c0 ? s : i0;
  d0 = fminf(d, d0);
  d1 = n1;
  d2 = n2;
}

// ------------------------------------------- fused 3-NN + interpolate + concat
// Round-10 proven config (best measured: 73.9us): 16 chunks x 128 candidates
// per point-pair (Q=2), 512-thread blocks, 8192 waves total. Exact f32 keys.
// Also folds: weight->bf16 conversion, BN-stats zeroing (block 0,0).
__global__ __launch_bounds__(512) void knn_interp_kernel(
    const float* __restrict__ xyz1, const float* __restrict__ xyz2,
    const float* __restrict__ points1, const float* __restrict__ points2,
    u16* __restrict__ xcat,
    const float* __restrict__ w0, const float* __restrict__ w1,
    u16* __restrict__ w0b, u16* __restrict__ w1b,
    float* __restrict__ stats) {
  __shared__ float4 sp[16 * 131];   // stride 131: chunk bases 2-way bank alias (free)
  const int b = blockIdx.y;
  const int t = threadIdx.x;
  {  // folded weight conversion: 131072 elements over 524288 threads
    int gid = (b * gridDim.x + blockIdx.x) * 512 + t;
    if (gid < 256 * INCH) w0b[gid] = f2bf(w0[gid]);
    else if (gid < 256 * INCH + 128 * 256) {
      int k2 = gid - 256 * INCH;
      w1b[k2] = f2bf(w1[k2]);
    }
  }
  if (blockIdx.x == 0 && b == 0) {          // folded stats zeroing (replays!)
    for (int i = t; i < 768; i += 512) stats[i] = 0.f;
  }
#pragma unroll
  for (int k = 0; k < 4; ++k) {
    int s = t + k * 512;
    const float* q = xyz2 + ((size_t)b * S_ + s) * 3;
    float x = q[0], y = q[1], z = q[2];
    sp[(s >> 7) * 131 + (s & 127)] = make_float4(x, y, z, fmaf(x, x, fmaf(y, y, z * z)));
  }
  __syncthreads();
  const int pw = t >> 4;     // point-pair within block [0,32)
  const int ck = t & 15;     // S-chunk [0,16)
  const int n0 = blockIdx.x * 64 + pw * 2;
  const int p0 = b * N_ + n0;
  const int p1 = p0 + 1;
  const float ax = xyz1[p0 * 3 + 0], ay = xyz1[p0 * 3 + 1], az = xyz1[p0 * 3 + 2];
  const float bx = xyz1[p1 * 3 + 0], by = xyz1[p1 * 3 + 1], bz = xyz1[p1 * 3 + 2];
  const float nxa = -2.f * ax, nya = -2.f * ay, nza = -2.f * az;
  const float nxb = -2.f * bx, nyb = -2.f * by, nzb = -2.f * bz;
  const float p2a = fmaf(ax, ax, fmaf(ay, ay, az * az));
  const float p2b = fmaf(bx, bx, fmaf(by, by, bz * bz));
  float a0 = 3e38f, a1 = 3e38f, a2 = 3e38f;
  float b0 = 3e38f, b1 = 3e38f, b2 = 3e38f;
  int ai0 = 0, ai1 = 0, ai2 = 0;
  int bi0 = 0, bi1 = 0, bi2 = 0;
  const float4* bp = &sp[ck * 131];
  for (int s = 0; s < 128; s += 4) {
#pragma unroll
    for (int j = 0; j < 4; ++j) {
      float4 q = bp[s + j];
      float base = fmaf(q.z, nza, q.w);
      float ka = fmaf(q.x, nxa, fmaf(q.y, nya, base));
      top3_bl(ka, s + j, a0, a1, a2, ai0, ai1, ai2);
      float baseb = fmaf(q.z, nzb, q.w);
      float kb = fmaf(q.x, nxb, fmaf(q.y, nyb, baseb));
      top3_bl(kb, s + j, b0, b1, b2, bi0, bi1, bi2);
    }
  }
  const int soff = ck * 128;
  ai0 += soff; ai1 += soff; ai2 += soff;
  bi0 += soff; bi1 += soff; bi2 += soff;
  // XOR-butterfly merge: after masks 1,2,4,8 all 16 lanes hold the merged top-3
#pragma unroll
  for (int m = 1; m <= 8; m <<= 1) {
    float e0 = __shfl_xor(a0, m), e1 = __shfl_xor(a1, m), e2 = __shfl_xor(a2, m);
    int j0 = __shfl_xor(ai0, m), j1 = __shfl_xor(ai1, m), j2 = __shfl_xor(ai2, m);
    top3_bl(e0, j0, a0, a1, a2, ai0, ai1, ai2);
    top3_bl(e1, j1, a0, a1, a2, ai0, ai1, ai2);
    top3_bl(e2, j2, a0, a1, a2, ai0, ai1, ai2);
    float f0 = __shfl_xor(b0, m), f1 = __shfl_xor(b1, m), f2 = __shfl_xor(b2, m);
    int k0 = __shfl_xor(bi0, m), k1 = __shfl_xor(bi1, m), k2 = __shfl_xor(bi2, m);
    top3_bl(f0, k0, b0, b1, b2, bi0, bi1, bi2);
    top3_bl(f1, k1, b0, b1, b2, bi0, bi1, bi2);
    top3_bl(f2, k2, b0, b1, b2, bi0, bi1, bi2);
  }
  // ---- interpolation weights (computed redundantly in all 16 lanes)
  float da0 = fmaxf(a0 + p2a, 1e-10f);
  float da1 = fmaxf(a1 + p2a, 1e-10f);
  float da2 = fmaxf(a2 + p2a, 1e-10f);
  float v0 = 1.f / da0, v1 = 1.f / da1, v2 = 1.f / da2;
  float inv = 1.f / (v0 + v1 + v2);
  const float wa0 = v0 * inv, wa1 = v1 * inv, wa2 = v2 * inv;
  float db0 = fmaxf(b0 + p2b, 1e-10f);
  float db1 = fmaxf(b1 + p2b, 1e-10f);
  float db2 = fmaxf(b2 + p2b, 1e-10f);
  float u0 = 1.f / db0, u1 = 1.f / db1, u2 = 1.f / db2;
  float uin = 1.f / (u0 + u1 + u2);
  const float wb0 = u0 * uin, wb1 = u1 * uin, wb2 = u2 * uin;
  // ---- gather + concat: lane ck covers channel chunks {j*16+ck}
  const float* P2b = points2 + (size_t)b * S_ * D2_;
#pragma unroll
  for (int pt = 0; pt < 2; ++pt) {
    const int p = pt ? p1 : p0;
    const float w_0 = pt ? wb0 : wa0, w_1 = pt ? wb1 : wa1, w_2 = pt ? wb2 : wa2;
    const float* Q0 = P2b + (size_t)(pt ? bi0 : ai0) * D2_;
    const float* Q1 = P2b + (size_t)(pt ? bi1 : ai1) * D2_;
    const float* Q2 = P2b + (size_t)(pt ? bi2 : ai2) * D2_;
    u16* xr = xcat + (size_t)p * INCH;
    const float4* P1 = (const float4*)(points1 + (size_t)p * D1_);
#pragma unroll
    for (int j = 0; j < 2; ++j) {       // points1 half: 32 float4 over 16 lanes
      int cchunk = j * 16 + ck;
      float4 v = P1[cchunk];
      *(uint2*)&xr[cchunk * 4] = make_uint2(pack2(v.x, v.y), pack2(v.z, v.w));
    }
#pragma unroll
    for (int j = 0; j < 4; ++j) {       // interp half: 64 float4 over 16 lanes
      int cchunk = j * 16 + ck;
      float4 qa = *(const float4*)(Q0 + cchunk * 4);
      float4 qb = *(const float4*)(Q1 + cchunk * 4);
      float4 qc = *(const float4*)(Q2 + cchunk * 4);
      float r0 = fmaf(w_0, qa.x, fmaf(w_1, qb.x, w_2 * qc.x));
      float r1 = fmaf(w_0, qa.y, fmaf(w_1, qb.y, w_2 * qc.y));
      float r2 = fmaf(w_0, qa.z, fmaf(w_1, qb.z, w_2 * qc.z));
      float r3 = fmaf(w_0, qa.w, fmaf(w_1, qb.w, w_2 * qc.w));
      *(uint2*)&xr[D1_ + cchunk * 4] = make_uint2(pack2(r0, r1), pack2(r2, r3));
    }
  }
}

// ---------------------------------------------------------------- MFMA GEMM
// C[M,NT] = A[M,K] * W[NT,K]^T, FULL-WIDTH N tile (A read exactly once).
// BM=128, BN=NT, BK=64. THREADS = NT*2. Wave tile 64x64, acc[4][4] f32x4.
// FUSE: prologue computes BN scale/shift IN-KERNEL from gsum/gsq+gamma/beta
// (stats final at kernel boundary) — kills the bn_finalize launch; A-staging
// then applies BN+ReLU in regs. Non-FUSE uses global_load_lds w=16.
// NOTE: no __threadfence / in-kernel stats finalize for OWN stats (round-4
// lesson: per-block agent-scope release = buffer_wbl2 serialization).
template <int K, int NT, bool FUSE, int MW>
__global__ __launch_bounds__(NT * 2, MW) void gemm_bn(const u16* __restrict__ A,
                                                      const u16* __restrict__ W,
                                                      u16* __restrict__ Y,
                                                      float* __restrict__ gsum,
                                                      float* __restrict__ gsq,
                                                      const float* __restrict__ bnsum,
                                                      const float* __restrict__ bnsq,
                                                      const float* __restrict__ bngam,
                                                      const float* __restrict__ bnbet) {
  constexpr int THREADS = NT * 2;
  constexpr int RPP = THREADS / 8;   // rows per staging pass (8 thr x 16B = 64 cols)
  constexpr int AP = 128 / RPP;      // A staging passes
  constexpr int WP = NT / RPP;       // W staging passes
  constexpr int WCN = NT / 64;       // wave columns
  __shared__ u16 As[128 * 64];
  __shared__ u16 Ws[NT * 64];
  __shared__ float s_sum[NT];
  __shared__ float s_sq[NT];
  __shared__ float s_scale[FUSE ? K : 1];
  __shared__ float s_shift[FUSE ? K : 1];
  const int tid = threadIdx.x;
  const int lane = tid & 63, wid = tid >> 6;
  const int wr = wid / WCN, wc = wid % WCN;
  const int brow = blockIdx.x * 128;
  const int rr = tid >> 3, ss = tid & 7;
  const int ch = ss ^ (rr & 7);            // inverse-swizzled source chunk
  f32x4 acc[4][4] = {};

  if constexpr (FUSE) {
    // K == 256 == THREADS: one channel per thread
    float sm = bnsum[tid] * (1.f / 65536.f);
    float vr = bnsq[tid] * (1.f / 65536.f) - sm * sm;   // biased, as reference
    float sc = bngam[tid] * rsqrtf(vr + 1e-5f);
    s_scale[tid] = sc;
    s_shift[tid] = bnbet[tid] - sm * sc;
    __syncthreads();
  }

  for (int kt = 0; kt < K / 64; ++kt) {
    if (kt) __syncthreads();
    if constexpr (FUSE) {
      const float4 sc0 = *(const float4*)&s_scale[kt * 64 + ch * 8];
      const float4 sc1 = *(const float4*)&s_scale[kt * 64 + ch * 8 + 4];
      const float4 sh0 = *(const float4*)&s_shift[kt * 64 + ch * 8];
      const float4 sh1 = *(const float4*)&s_shift[kt * 64 + ch * 8 + 4];
#pragma unroll
      for (int it = 0; it < AP; ++it) {
        int row = it * RPP + rr;
        uint4 raw = *(const uint4*)&A[(size_t)(brow + row) * K + kt * 64 + ch * 8];
        auto bnr = [](unsigned u, float s, float t) {
          return fmaxf(fmaf(bf2f((u16)u), s, t), 0.f);
        };
        unsigned o0 = pack2(bnr(raw.x & 0xffff, sc0.x, sh0.x), bnr(raw.x >> 16, sc0.y, sh0.y));
        unsigned o1 = pack2(bnr(raw.y & 0xffff, sc0.z, sh0.z), bnr(raw.y >> 16, sc0.w, sh0.w));
        unsigned o2 = pack2(bnr(raw.z & 0xffff, sc1.x, sh1.x), bnr(raw.z >> 16, sc1.y, sh1.y));
        unsigned o3 = pack2(bnr(raw.w & 0xffff, sc1.z, sh1.z), bnr(raw.w >> 16, sc1.w, sh1.w));
        *(uint4*)((char*)As + (size_t)(it * THREADS + tid) * 16) = make_uint4(o0, o1, o2, o3);
      }
    } else {
#pragma unroll
      for (int it = 0; it < AP; ++it) {
        int row = it * RPP + rr;
        async16(&A[(size_t)(brow + row) * K + kt * 64 + ch * 8], &As[(it * THREADS + tid) * 8]);
      }
    }
#pragma unroll
    for (int it = 0; it < WP; ++it) {
      int row = it * RPP + rr;
      async16(&W[(size_t)row * K + kt * 64 + ch * 8], &Ws[(it * THREADS + tid) * 8]);
    }
    __syncthreads();
#pragma unroll
    for (int ks = 0; ks < 2; ++ks) {
      bf16x8 af[4], wf[4];
#pragma unroll
      for (int i = 0; i < 4; ++i) {
        int ra = wr * 64 + i * 16 + (lane & 15);
        int ca = ks * 4 + (lane >> 4);
        af[i] = *(const bf16x8*)&As[ra * 64 + ((ca ^ (ra & 7)) * 8)];
        int rw = wc * 64 + i * 16 + (lane & 15);
        wf[i] = *(const bf16x8*)&Ws[rw * 64 + ((ca ^ (rw & 7)) * 8)];
      }
#pragma unroll
      for (int mi = 0; mi < 4; ++mi)
#pragma unroll
        for (int ni = 0; ni < 4; ++ni)
          acc[mi][ni] = __builtin_amdgcn_mfma_f32_16x16x32_bf16(af[mi], wf[ni], acc[mi][ni], 0, 0, 0);
    }
  }

  // epilogue: store bf16 + block-level BN partial sums
  __syncthreads();
  if (tid < NT) { s_sum[tid] = 0.f; s_sq[tid] = 0.f; }
  __syncthreads();
#pragma unroll
  for (int ni = 0; ni < 4; ++ni) {
    int coll = wc * 64 + ni * 16 + (lane & 15);
    float ps = 0.f, pq = 0.f;
#pragma unroll
    for (int mi = 0; mi < 4; ++mi) {
      int rowl = wr * 64 + mi * 16 + ((lane >> 4) << 2);
#pragma unroll
      for (int q = 0; q < 4; ++q) {
        float v = acc[mi][ni][q];
        ps += v; pq += v * v;
        Y[(size_t)(brow + rowl + q) * NT + coll] = f2bf(v);
      }
    }
    atomicAdd(&s_sum[coll], ps);
    atomicAdd(&s_sq[coll], pq);
  }
  __syncthreads();
  if (tid < NT) {
    unsafeAtomicAdd(&gsum[tid], s_sum[tid]);
    unsafeAtomicAdd(&gsq[tid], s_sq[tid]);
  }
}

// ------------------------------------------------- BN+ReLU -> f32 output
// Prologue computes scale/shift from stats in-kernel (stats final at kernel
// boundary) — kills the second bn_finalize launch.
__global__ __launch_bounds__(256) void bn_out_kernel(const u16* __restrict__ y,
                                                     const float* __restrict__ gsum,
                                                     const float* __restrict__ gsq,
                                                     const float* __restrict__ gamma,
                                                     const float* __restrict__ beta,
                                                     float* __restrict__ out) {
  __shared__ float s_sc[128], s_sh[128];
  if (threadIdx.x < 128) {
    int c = threadIdx.x;
    float sm = gsum[c] * (1.f / 65536.f);
    float vr = gsq[c] * (1.f / 65536.f) - sm * sm;   // biased, as reference
    float sc = gamma[c] * rsqrtf(vr + 1e-5f);
    s_sc[c] = sc;
    s_sh[c] = beta[c] - sm * sc;
  }
  __syncthreads();
  const int idx = blockIdx.x * 256 + threadIdx.x;
  uint4 v = ((const uint4*)y)[idx];
  const int c0 = (idx * 8) & 127;
  unsigned w[4] = {v.x, v.y, v.z, v.w};
  float o[8];
#pragma unroll
  for (int j = 0; j < 4; ++j) {
    o[2 * j]     = fmaxf(fmaf(bf2f((u16)(w[j] & 0xffff)), s_sc[c0 + 2 * j],     s_sh[c0 + 2 * j]),     0.f);
    o[2 * j + 1] = fmaxf(fmaf(bf2f((u16)(w[j] >> 16)),    s_sc[c0 + 2 * j + 1], s_sh[c0 + 2 * j + 1]), 0.f);
  }
  float4* op = (float4*)(out + (size_t)idx * 8);
  op[0] = make_float4(o[0], o[1], o[2], o[3]);
  op[1] = make_float4(o[4], o[5], o[6], o[7]);
}

extern "C" void kernel_launch(void* const* d_in, const int* in_sizes, int n_in,
                              void* d_out, int out_size, void* d_ws, size_t ws_size,
                              hipStream_t stream) {
  const float* xyz1    = (const float*)d_in[0];
  const float* xyz2    = (const float*)d_in[1];
  const float* points1 = (const float*)d_in[2];
  const float* points2 = (const float*)d_in[3];
  const float* w0      = (const float*)d_in[4];
  // b0 (d_in[5]) / b1 (d_in[9]) are mathematically cancelled by training-mode BN
  const float* gamma0  = (const float*)d_in[6];
  const float* beta0   = (const float*)d_in[7];
  const float* w1      = (const float*)d_in[8];
  const float* gamma1  = (const float*)d_in[10];
  const float* beta1   = (const float*)d_in[11];

  char* ws = (char*)d_ws;
  u16* xcat = (u16*)ws;  ws += (size_t)M_ * INCH * 2;   // 50.3 MB
  u16* y0   = (u16*)ws;  ws += (size_t)M_ * 256 * 2;    // 33.6 MB
  u16* y1   = (u16*)ws;  ws += (size_t)M_ * 128 * 2;    // 16.8 MB
  u16* w0b = (u16*)ws;   ws += 256 * INCH * 2;
  u16* w1b = (u16*)ws;   ws += 128 * 256 * 2;
  float* stats = (float*)ws; ws += 768 * 4;  // sum0[256] sq0[256] sum1[128] sq1[128]

  float* sum0 = stats,       *sq0 = stats + 256;
  float* sum1 = stats + 512, *sq1 = stats + 640;

  // stats zeroing is folded into knn_interp block (0,0) — no memset dispatch

  knn_interp_kernel<<<dim3(N_ / 64, B_), 512, 0, stream>>>(
      xyz1, xyz2, points1, points2, xcat, w0, w1, w0b, w1b, stats);

  gemm_bn<INCH, 256, false, 4><<<dim3(M_ / 128), 512, 0, stream>>>(
      xcat, w0b, y0, sum0, sq0, nullptr, nullptr, nullptr, nullptr);

  // gemm2 consumes RAW y0; BN0 scale/shift computed in-kernel from stats
  gemm_bn<256, 128, true, 2><<<dim3(M_ / 128), 256, 0, stream>>>(
      y0, w1b, y1, sum1, sq1, sum0, sq0, gamma0, beta0);

  // bn_out computes BN1 scale/shift in-kernel from stats
  bn_out_kernel<<<(M_ * 128 / 8) / 256, 256, 0, stream>>>(
      y1, sum1, sq1, gamma1, beta1, (float*)d_out);
}